// Round 12
// baseline (59.195 us; speedup 1.0000x reference)
//
#include <hip/hip_runtime.h>
#include <math.h>

// DETR HungarianMatcher — round 12: DIAGNOSTIC (R7 body x3 in one dispatch).
// Iterations 0,1 write to d_ws regions, iteration 2 writes d_out (idempotent,
// same math). Purpose: make the kernel the top-1 dispatch (>40us) so rocprof
// exposes its VALUBusy / hbm_gbps / LDS conflicts, which have been hidden
// behind the harness poison-fills since R1. Perf this round is sacrificial.

#define NROWS 16000
#define NC 92
#define M_TGT 1024
#define TPB 256
#define ROWS 8
#define REPEAT 3

typedef float f32x4 __attribute__((ext_vector_type(4)));

__global__ __launch_bounds__(TPB, 6) void hungarian_cost_kernel(
    const float* __restrict__ logits,   // [NROWS, NC]
    const float* __restrict__ pboxes,   // [NROWS, 4] cxcywh
    const float* __restrict__ tboxes,   // [M_TGT, 4] cxcywh
    const int*   __restrict__ tlabels,  // [M_TGT]
    float* __restrict__ o0,             // iteration 0 sink (ws)
    float* __restrict__ o1,             // iteration 1 sink (ws)
    float* __restrict__ o2)             // iteration 2 = real out
{
    const int n0 = blockIdx.x * ROWS;
    const int t = threadIdx.x;
    const int lane = t & 63;
    const int wid  = t >> 6;

    __shared__ float negp[ROWS][NC];   // 2 - softmax prob

    // ---- per-thread target context (registers), m = 4t + k — load once ----
    float tcx[4], tcy[4], twd[4], tht[4];
    float bx0[4], by0[4], bx1[4], by1[4], areab[4];
    const int4 lb4 = reinterpret_cast<const int4*>(tlabels)[t];
    int lbl[4] = {lb4.x, lb4.y, lb4.z, lb4.w};
    #pragma unroll
    for (int k = 0; k < 4; ++k) {
        const float4 tb = reinterpret_cast<const float4*>(tboxes)[4 * t + k];
        tcx[k] = tb.x; tcy[k] = tb.y; twd[k] = tb.z; tht[k] = tb.w;
        bx0[k] = fmaf(-0.5f, tb.z, tb.x);  by0[k] = fmaf(-0.5f, tb.w, tb.y);
        bx1[k] = fmaf( 0.5f, tb.z, tb.x);  by1[k] = fmaf( 0.5f, tb.w, tb.y);
        areab[k] = tb.z * tb.w;
        lbl[k] = (lbl[k] < 0) ? 0 : (lbl[k] > NC - 1 ? NC - 1 : lbl[k]);
    }

    #pragma unroll 1
    for (int it = 0; it < REPEAT; ++it) {
        float* __restrict__ ob = (it == 0) ? o0 : (it == 1) ? o1 : o2;

        // ---- softmax: wave `wid` handles rows 2*wid, 2*wid+1 ----
        #pragma unroll
        for (int j = 0; j < 2; ++j) {
            const int r = wid * 2 + j;
            const float* lg = logits + (size_t)(n0 + r) * NC;
            const float x0 = lg[lane];
            const bool  hi = (lane < NC - 64);
            const float x1 = hi ? lg[64 + lane] : -INFINITY;
            float mx = fmaxf(x0, x1);
            #pragma unroll
            for (int off = 32; off >= 1; off >>= 1)
                mx = fmaxf(mx, __shfl_xor(mx, off));
            const float e0 = __expf(x0 - mx);
            const float e1 = hi ? __expf(x1 - mx) : 0.0f;
            float s = e0 + e1;
            #pragma unroll
            for (int off = 32; off >= 1; off >>= 1)
                s += __shfl_xor(s, off);
            const float rs = __builtin_amdgcn_rcpf(s);
            negp[r][lane] = fmaf(-e0, rs, 2.0f);
            if (hi) negp[r][64 + lane] = fmaf(-e1, rs, 2.0f);
        }
        __syncthreads();

        // ---- software-pipelined main loop over 8 rows (R7 body) ----
        float cls[4];
        #pragma unroll
        for (int k = 0; k < 4; ++k) cls[k] = negp[0][lbl[k]];
        float4 pb = reinterpret_cast<const float4*>(pboxes)[n0];

        #pragma unroll
        for (int r = 0; r < ROWS; ++r) {
            float clsN[4];
            float4 pbN;
            if (r + 1 < ROWS) {
                #pragma unroll
                for (int k = 0; k < 4; ++k) clsN[k] = negp[r + 1][lbl[k]];
                pbN = reinterpret_cast<const float4*>(pboxes)[n0 + r + 1];
            }

            const float ax0 = fmaf(-0.5f, pb.z, pb.x);
            const float ay0 = fmaf(-0.5f, pb.w, pb.y);
            const float ax1 = fmaf( 0.5f, pb.z, pb.x);
            const float ay1 = fmaf( 0.5f, pb.w, pb.y);
            const float area_a = pb.z * pb.w;

            float tmp[4];
            #pragma unroll
            for (int k = 0; k < 4; ++k) {
                const float cb = fabsf(pb.x - tcx[k]) + fabsf(pb.y - tcy[k])
                               + fabsf(pb.z - twd[k]) + fabsf(pb.w - tht[k]);
                const float iwu = fminf(ax1, bx1[k]) - fmaxf(ax0, bx0[k]);
                const float ihu = fminf(ay1, by1[k]) - fmaxf(ay0, by0[k]);
                const float inter = fmaxf(iwu, 0.0f) * fmaxf(ihu, 0.0f);
                const float uni = area_a + areab[k] - inter;
                const float ew = pb.z + twd[k] - iwu;
                const float eh = pb.w + tht[k] - ihu;
                const float ae = ew * eh;
                const float h = fmaf(inter, __builtin_amdgcn_rcpf(uni),
                                     uni * __builtin_amdgcn_rcpf(ae));
                tmp[k] = fmaf(5.0f, cb, cls[k]) - 2.0f * h;
            }
            f32x4 res = {tmp[0], tmp[1], tmp[2], tmp[3]};
            __builtin_nontemporal_store(res,
                reinterpret_cast<f32x4*>(ob + ((size_t)(n0 + r) << 10)) + t);

            #pragma unroll
            for (int k = 0; k < 4; ++k) cls[k] = clsN[k];
            pb = pbN;
        }
        __syncthreads();   // protect negp rewrite next iteration
    }
}

extern "C" void kernel_launch(void* const* d_in, const int* in_sizes, int n_in,
                              void* d_out, int out_size, void* d_ws, size_t ws_size,
                              hipStream_t stream) {
    const float* logits  = (const float*)d_in[0];  // [16,1000,92]
    const float* pboxes  = (const float*)d_in[1];  // [16,1000,4]
    const float* tboxes  = (const float*)d_in[2];  // [1024,4]
    const int*   tlabels = (const int*)d_in[3];    // [1024]
    float* out = (float*)d_out;                    // [16,1000,1024]

    const size_t out_bytes = (size_t)NROWS * M_TGT * sizeof(float);
    float* w0 = (float*)d_ws;
    float* w1 = (ws_size >= 2 * out_bytes) ? (float*)((char*)d_ws + out_bytes)
                                           : (float*)d_ws;
    if (ws_size < out_bytes) { w0 = out; w1 = out; }  // degenerate fallback

    hungarian_cost_kernel<<<NROWS / ROWS, TPB, 0, stream>>>(
        logits, pboxes, tboxes, tlabels, w0, w1, out);
}

// Round 13
// 24.343 us; speedup vs baseline: 2.4317x; 2.4317x over previous
//
#include <hip/hip_runtime.h>
#include <math.h>

// DETR HungarianMatcher cost matrix on MI355X — round 13.
// EXACT R7 structure (best: 22.4us), single variable changed: nontemporal
// store -> regular float4 store. R12 diagnostic showed the kernel is
// write-path-bound at ~3.4 TB/s while regular-store fills hit 6.5 TB/s;
// suspect = NT bypassing L2's write-combining.

#define NROWS 16000
#define NC 92
#define M_TGT 1024
#define TPB 256
#define ROWS 8
#define KPT 4   // consecutive targets per thread (KPT*TPB == M_TGT)

typedef float f32x4 __attribute__((ext_vector_type(4)));

__global__ __launch_bounds__(TPB, 6) void hungarian_cost_kernel(
    const float* __restrict__ logits,   // [NROWS, NC]
    const float* __restrict__ pboxes,   // [NROWS, 4] cxcywh
    const float* __restrict__ tboxes,   // [M_TGT, 4] cxcywh
    const int*   __restrict__ tlabels,  // [M_TGT]
    float* __restrict__ out)            // [NROWS, M_TGT]
{
    const int n0 = blockIdx.x * ROWS;
    const int t = threadIdx.x;
    const int lane = t & 63;
    const int wid  = t >> 6;

    __shared__ float negp[ROWS][NC];   // 2 - softmax prob

    // ---- softmax: wave `wid` handles rows 2*wid, 2*wid+1 ----
    #pragma unroll
    for (int j = 0; j < 2; ++j) {
        const int r = wid * 2 + j;
        const float* lg = logits + (size_t)(n0 + r) * NC;
        const float x0 = lg[lane];                 // lanes 0..63
        const bool  hi = (lane < NC - 64);         // lanes 0..27 cover 64..91
        const float x1 = hi ? lg[64 + lane] : -INFINITY;
        float mx = fmaxf(x0, x1);
        #pragma unroll
        for (int off = 32; off >= 1; off >>= 1)
            mx = fmaxf(mx, __shfl_xor(mx, off));
        const float e0 = __expf(x0 - mx);
        const float e1 = hi ? __expf(x1 - mx) : 0.0f;
        float s = e0 + e1;
        #pragma unroll
        for (int off = 32; off >= 1; off >>= 1)
            s += __shfl_xor(s, off);
        const float rs = __builtin_amdgcn_rcpf(s);
        negp[r][lane] = fmaf(-e0, rs, 2.0f);
        if (hi) negp[r][64 + lane] = fmaf(-e1, rs, 2.0f);
    }

    // ---- per-thread target context (registers), m = 4t + k ----
    float tcx[KPT], tcy[KPT], twd[KPT], tht[KPT];
    float bx0[KPT], by0[KPT], bx1[KPT], by1[KPT], areab[KPT];
    const int4 lb4 = reinterpret_cast<const int4*>(tlabels)[t];
    int lbl[KPT] = {lb4.x, lb4.y, lb4.z, lb4.w};
    #pragma unroll
    for (int k = 0; k < KPT; ++k) {
        const float4 tb = reinterpret_cast<const float4*>(tboxes)[4 * t + k];
        tcx[k] = tb.x; tcy[k] = tb.y; twd[k] = tb.z; tht[k] = tb.w;
        bx0[k] = fmaf(-0.5f, tb.z, tb.x);  by0[k] = fmaf(-0.5f, tb.w, tb.y);
        bx1[k] = fmaf( 0.5f, tb.z, tb.x);  by1[k] = fmaf( 0.5f, tb.w, tb.y);
        areab[k] = tb.z * tb.w;
        lbl[k] = (lbl[k] < 0) ? 0 : (lbl[k] > NC - 1 ? NC - 1 : lbl[k]);
    }
    __syncthreads();

    // ---- software-pipelined main loop over 8 rows ----
    float cls[KPT];
    #pragma unroll
    for (int k = 0; k < KPT; ++k) cls[k] = negp[0][lbl[k]];
    float4 pb = reinterpret_cast<const float4*>(pboxes)[n0];   // uniform

    #pragma unroll
    for (int r = 0; r < ROWS; ++r) {
        // prefetch next row's gathers + pred box (independent of this row)
        float clsN[KPT];
        float4 pbN;
        if (r + 1 < ROWS) {
            #pragma unroll
            for (int k = 0; k < KPT; ++k) clsN[k] = negp[r + 1][lbl[k]];
            pbN = reinterpret_cast<const float4*>(pboxes)[n0 + r + 1];
        }

        const float ax0 = fmaf(-0.5f, pb.z, pb.x);
        const float ay0 = fmaf(-0.5f, pb.w, pb.y);
        const float ax1 = fmaf( 0.5f, pb.z, pb.x);
        const float ay1 = fmaf( 0.5f, pb.w, pb.y);
        const float area_a = pb.z * pb.w;

        float tmp[KPT];
        #pragma unroll
        for (int k = 0; k < KPT; ++k) {
            const float cb = fabsf(pb.x - tcx[k]) + fabsf(pb.y - tcy[k])
                           + fabsf(pb.z - twd[k]) + fabsf(pb.w - tht[k]);
            const float iwu = fminf(ax1, bx1[k]) - fmaxf(ax0, bx0[k]);
            const float ihu = fminf(ay1, by1[k]) - fmaxf(ay0, by0[k]);
            const float inter = fmaxf(iwu, 0.0f) * fmaxf(ihu, 0.0f);
            const float uni = area_a + areab[k] - inter;
            const float ew = pb.z + twd[k] - iwu;   // max(a1,b1)-min(a0,b0)
            const float eh = pb.w + tht[k] - ihu;
            const float ae = ew * eh;
            const float h = fmaf(inter, __builtin_amdgcn_rcpf(uni),
                                 uni * __builtin_amdgcn_rcpf(ae));
            tmp[k] = fmaf(5.0f, cb, cls[k]) - 2.0f * h;
        }
        float4 res = {tmp[0], tmp[1], tmp[2], tmp[3]};
        reinterpret_cast<float4*>(out + ((size_t)(n0 + r) << 10))[t] = res;  // REGULAR store

        #pragma unroll
        for (int k = 0; k < KPT; ++k) cls[k] = clsN[k];
        pb = pbN;
    }
}

extern "C" void kernel_launch(void* const* d_in, const int* in_sizes, int n_in,
                              void* d_out, int out_size, void* d_ws, size_t ws_size,
                              hipStream_t stream) {
    const float* logits  = (const float*)d_in[0];  // [16,1000,92]
    const float* pboxes  = (const float*)d_in[1];  // [16,1000,4]
    const float* tboxes  = (const float*)d_in[2];  // [1024,4]
    const int*   tlabels = (const int*)d_in[3];    // [1024]
    float* out = (float*)d_out;                    // [16,1000,1024]

    hungarian_cost_kernel<<<NROWS / ROWS, TPB, 0, stream>>>(
        logits, pboxes, tboxes, tlabels, out);
}